// Round 7
// baseline (190.436 us; speedup 1.0000x reference)
//
#include <hip/hip_runtime.h>

// LAYER_IDX = [0, 4096, 6144, 7168, 7680, 7682]
// L1: 4096->2048 ebase 0       | L2: 2048->1024 ebase 262144
// L3: 1024->512  ebase 393216  | out: 512->2    ebase 458752
// v7: SINGLE-LAUNCH monolith. Computation is independent per batch column
// (LN is over nodes per column), so each block owns 4 columns and runs the
// whole network out of LDS: no grid sync, no atomics, no workspace, no
// inter-block communication of any kind. Edges stream from global (L2).
#define FAN_IN 128
#define EPS 1e-5f

typedef unsigned short u16;
typedef unsigned int u32;

__device__ __forceinline__ u16 f2bf(float f) {   // fp32->bf16 RNE
    union { float f; u32 u; } v; v.f = f;
    u32 r = v.u + 0x7fffu + ((v.u >> 16) & 1u);
    return (u16)(r >> 16);
}
__device__ __forceinline__ float bflo(u32 u) { return __uint_as_float(u << 16); }
__device__ __forceinline__ float bfhi(u32 u) { return __uint_as_float(u & 0xffff0000u); }

// 4 edges' worth of gather: one ds_read_b64 per edge (4 bf16 cols), 4 FMA.
#define EDGE4(S, W, PANEL)                                   \
    {                                                        \
        const uint2 vv = *(const uint2*)&PANEL[(S) * 4];     \
        a0 = fmaf((W), bflo(vv.x), a0);                      \
        a1 = fmaf((W), bfhi(vv.x), a1);                      \
        a2 = fmaf((W), bflo(vv.y), a2);                      \
        a3 = fmaf((W), bfhi(vv.y), a3);                      \
    }

// block-wide stats: wave shfl-reduce 8 values -> SW[wave][8] -> MR[8]
// MR[0..3] = mean per col, MR[4..7] = rstd per col.
#define STATS_REDUCE(INVM)                                                   \
    {                                                                        \
        _Pragma("unroll")                                                    \
        for (int o = 32; o; o >>= 1) {                                       \
            sA[0] += __shfl_down(sA[0], o); sQ[0] += __shfl_down(sQ[0], o);  \
            sA[1] += __shfl_down(sA[1], o); sQ[1] += __shfl_down(sQ[1], o);  \
            sA[2] += __shfl_down(sA[2], o); sQ[2] += __shfl_down(sQ[2], o);  \
            sA[3] += __shfl_down(sA[3], o); sQ[3] += __shfl_down(sQ[3], o);  \
        }                                                                    \
        if (lane == 0) {                                                     \
            SW[wv][0] = sA[0]; SW[wv][1] = sA[1];                            \
            SW[wv][2] = sA[2]; SW[wv][3] = sA[3];                            \
            SW[wv][4] = sQ[0]; SW[wv][5] = sQ[1];                            \
            SW[wv][6] = sQ[2]; SW[wv][7] = sQ[3];                            \
        }                                                                    \
        __syncthreads();                                                     \
        if (tid < 4) {                                                       \
            float S = 0.f, Q = 0.f;                                          \
            _Pragma("unroll")                                                \
            for (int w = 0; w < 8; ++w) { S += SW[w][tid]; Q += SW[w][4 + tid]; } \
            const float m = S * (INVM);                                      \
            MR[tid] = m;                                                     \
            MR[4 + tid] = rsqrtf(Q * (INVM) - m * m + EPS);                  \
        }                                                                    \
        __syncthreads();                                                     \
    }

__global__ __launch_bounds__(512, 2) void mono(
    const float* __restrict__ x, const float* __restrict__ weight,
    const int* __restrict__ edge_src, const float* __restrict__ bias,
    const float* __restrict__ lng, const float* __restrict__ lnb,
    float* __restrict__ out) {
    __shared__ u16 A0[4096 * 4];     // 32 KB  x^T panel, bf16 [feat][4 cols]
    __shared__ u16 A1[2048 * 4];     // 16 KB  act1
    __shared__ u16 A2[1024 * 4];     //  8 KB  act2
    __shared__ u16 A3[512 * 4];      //  4 KB  act3
    __shared__ float SW[8][8];
    __shared__ float MR[8];
    __shared__ float OW[4][4];

    const int tid = threadIdx.x;
    const int wv = tid >> 6, lane = tid & 63;
    const int c0 = blockIdx.x * 4;

    // ---- stage x^T panel: 8 features/thread x 4 cols, f32 -> bf16 ----------
    {
        const int f0 = tid * 8;
        float v0[8], v1[8], v2[8], v3[8];
        *(float4*)&v0[0] = *(const float4*)(x + (size_t)(c0 + 0) * 4096 + f0);
        *(float4*)&v0[4] = *(const float4*)(x + (size_t)(c0 + 0) * 4096 + f0 + 4);
        *(float4*)&v1[0] = *(const float4*)(x + (size_t)(c0 + 1) * 4096 + f0);
        *(float4*)&v1[4] = *(const float4*)(x + (size_t)(c0 + 1) * 4096 + f0 + 4);
        *(float4*)&v2[0] = *(const float4*)(x + (size_t)(c0 + 2) * 4096 + f0);
        *(float4*)&v2[4] = *(const float4*)(x + (size_t)(c0 + 2) * 4096 + f0 + 4);
        *(float4*)&v3[0] = *(const float4*)(x + (size_t)(c0 + 3) * 4096 + f0);
        *(float4*)&v3[4] = *(const float4*)(x + (size_t)(c0 + 3) * 4096 + f0 + 4);
        u32 pk[16];
#pragma unroll
        for (int j = 0; j < 8; ++j) {
            pk[2 * j]     = (u32)f2bf(v0[j]) | ((u32)f2bf(v1[j]) << 16);
            pk[2 * j + 1] = (u32)f2bf(v2[j]) | ((u32)f2bf(v3[j]) << 16);
        }
#pragma unroll
        for (int qq = 0; qq < 4; ++qq)
            *(uint4*)&A0[(f0 + qq * 2) * 4] = *(const uint4*)&pk[qq * 4];
    }
    __syncthreads();

    // ================= P1: layer 1 (2048 nodes, 4 nodes/thread) ============
    float sA[4] = {0.f, 0.f, 0.f, 0.f}, sQ[4] = {0.f, 0.f, 0.f, 0.f};
    {
        float acc[4][4];
#pragma unroll
        for (int i = 0; i < 4; ++i) {
            const int n = tid + i * 512;
            const int eb = n * FAN_IN;
            float a0 = 0.f, a1 = 0.f, a2 = 0.f, a3 = 0.f;
#pragma unroll 2
            for (int k = 0; k < FAN_IN; k += 4) {
                const int4 s4 = *(const int4*)(edge_src + eb + k);
                const float4 w4 = *(const float4*)(weight + eb + k);
                EDGE4(s4.x, w4.x, A0); EDGE4(s4.y, w4.y, A0);
                EDGE4(s4.z, w4.z, A0); EDGE4(s4.w, w4.w, A0);
            }
            const float bv = bias[n];
            a0 += bv; a1 += bv; a2 += bv; a3 += bv;
            acc[i][0] = a0; acc[i][1] = a1; acc[i][2] = a2; acc[i][3] = a3;
            sA[0] += a0; sQ[0] += a0 * a0; sA[1] += a1; sQ[1] += a1 * a1;
            sA[2] += a2; sQ[2] += a2 * a2; sA[3] += a3; sQ[3] += a3 * a3;
        }
        STATS_REDUCE(1.f / 2048.f);
        const float m0 = MR[0], m1 = MR[1], m2 = MR[2], m3 = MR[3];
        const float r0 = MR[4], r1 = MR[5], r2 = MR[6], r3 = MR[7];
#pragma unroll
        for (int i = 0; i < 4; ++i) {
            const int n = tid + i * 512;
            const float g = lng[n], bb = lnb[n];
            uint2 pk;
            pk.x = (u32)f2bf(fmaxf(fmaf(g * (acc[i][0] - m0), r0, bb), 0.f))
                 | ((u32)f2bf(fmaxf(fmaf(g * (acc[i][1] - m1), r1, bb), 0.f)) << 16);
            pk.y = (u32)f2bf(fmaxf(fmaf(g * (acc[i][2] - m2), r2, bb), 0.f))
                 | ((u32)f2bf(fmaxf(fmaf(g * (acc[i][3] - m3), r3, bb), 0.f)) << 16);
            *(uint2*)&A1[n * 4] = pk;
        }
    }
    __syncthreads();

    // ================= P2: layer 2 (1024 nodes, 2 nodes/thread) ============
    sA[0] = sA[1] = sA[2] = sA[3] = 0.f;
    sQ[0] = sQ[1] = sQ[2] = sQ[3] = 0.f;
    {
        float acc[2][4];
#pragma unroll
        for (int i = 0; i < 2; ++i) {
            const int n = tid + i * 512;
            const int eb = 262144 + n * FAN_IN;
            float a0 = 0.f, a1 = 0.f, a2 = 0.f, a3 = 0.f;
#pragma unroll 2
            for (int k = 0; k < FAN_IN; k += 4) {
                const int4 s4 = *(const int4*)(edge_src + eb + k);
                const float4 w4 = *(const float4*)(weight + eb + k);
                EDGE4(s4.x - 4096, w4.x, A1); EDGE4(s4.y - 4096, w4.y, A1);
                EDGE4(s4.z - 4096, w4.z, A1); EDGE4(s4.w - 4096, w4.w, A1);
            }
            const float bv = bias[2048 + n];
            a0 += bv; a1 += bv; a2 += bv; a3 += bv;
            acc[i][0] = a0; acc[i][1] = a1; acc[i][2] = a2; acc[i][3] = a3;
            sA[0] += a0; sQ[0] += a0 * a0; sA[1] += a1; sQ[1] += a1 * a1;
            sA[2] += a2; sQ[2] += a2 * a2; sA[3] += a3; sQ[3] += a3 * a3;
        }
        STATS_REDUCE(1.f / 1024.f);
        const float m0 = MR[0], m1 = MR[1], m2 = MR[2], m3 = MR[3];
        const float r0 = MR[4], r1 = MR[5], r2 = MR[6], r3 = MR[7];
#pragma unroll
        for (int i = 0; i < 2; ++i) {
            const int n = tid + i * 512;
            const float g = lng[2048 + n], bb = lnb[2048 + n];
            uint2 pk;
            pk.x = (u32)f2bf(fmaxf(fmaf(g * (acc[i][0] - m0), r0, bb), 0.f))
                 | ((u32)f2bf(fmaxf(fmaf(g * (acc[i][1] - m1), r1, bb), 0.f)) << 16);
            pk.y = (u32)f2bf(fmaxf(fmaf(g * (acc[i][2] - m2), r2, bb), 0.f))
                 | ((u32)f2bf(fmaxf(fmaf(g * (acc[i][3] - m3), r3, bb), 0.f)) << 16);
            *(uint2*)&A2[n * 4] = pk;
        }
    }
    __syncthreads();

    // ================= P3: layer 3 (512 nodes, 1 node/thread) ==============
    sA[0] = sA[1] = sA[2] = sA[3] = 0.f;
    sQ[0] = sQ[1] = sQ[2] = sQ[3] = 0.f;
    {
        const int n = tid;
        const int eb = 393216 + n * FAN_IN;
        float a0 = 0.f, a1 = 0.f, a2 = 0.f, a3 = 0.f;
#pragma unroll 2
        for (int k = 0; k < FAN_IN; k += 4) {
            const int4 s4 = *(const int4*)(edge_src + eb + k);
            const float4 w4 = *(const float4*)(weight + eb + k);
            EDGE4(s4.x - 6144, w4.x, A2); EDGE4(s4.y - 6144, w4.y, A2);
            EDGE4(s4.z - 6144, w4.z, A2); EDGE4(s4.w - 6144, w4.w, A2);
        }
        const float bv = bias[3072 + n];
        a0 += bv; a1 += bv; a2 += bv; a3 += bv;
        sA[0] = a0; sQ[0] = a0 * a0; sA[1] = a1; sQ[1] = a1 * a1;
        sA[2] = a2; sQ[2] = a2 * a2; sA[3] = a3; sQ[3] = a3 * a3;
        STATS_REDUCE(1.f / 512.f);
        const float g = lng[3072 + n], bb = lnb[3072 + n];
        uint2 pk;
        pk.x = (u32)f2bf(fmaxf(fmaf(g * (a0 - MR[0]), MR[4], bb), 0.f))
             | ((u32)f2bf(fmaxf(fmaf(g * (a1 - MR[1]), MR[5], bb), 0.f)) << 16);
        pk.y = (u32)f2bf(fmaxf(fmaf(g * (a2 - MR[2]), MR[6], bb), 0.f))
             | ((u32)f2bf(fmaxf(fmaf(g * (a3 - MR[3]), MR[7], bb), 0.f)) << 16);
        *(uint2*)&A3[n * 4] = pk;
    }
    __syncthreads();

    // ================= P4: output (2 targets x 128 edges x 4 cols) =========
    if (tid < 256) {                 // waves 0,1 -> tgt0; waves 2,3 -> tgt1
        const int tgt = tid >> 7, k = tid & 127;
        const int e = 458752 + tgt * FAN_IN + k;
        const int s = edge_src[e] - 7168;
        const float w = weight[e];
        const uint2 vv = *(const uint2*)&A3[s * 4];
        float o0 = w * bflo(vv.x), o1 = w * bfhi(vv.x);
        float o2 = w * bflo(vv.y), o3 = w * bfhi(vv.y);
#pragma unroll
        for (int o = 32; o; o >>= 1) {
            o0 += __shfl_down(o0, o); o1 += __shfl_down(o1, o);
            o2 += __shfl_down(o2, o); o3 += __shfl_down(o3, o);
        }
        if (lane == 0) { OW[wv][0] = o0; OW[wv][1] = o1; OW[wv][2] = o2; OW[wv][3] = o3; }
    }
    __syncthreads();
    if (tid < 8) {
        const int c = tid & 3, tg = tid >> 2;
        const float r = OW[tg * 2][c] + OW[tg * 2 + 1][c] + bias[3584 + tg];
        out[(size_t)(c0 + c) * 2 + tg] = r;
    }
}

// ---------------------------------------------------------------------------
extern "C" void kernel_launch(void* const* d_in, const int* in_sizes, int n_in,
                              void* d_out, int out_size, void* d_ws, size_t ws_size,
                              hipStream_t stream) {
    const float* x        = (const float*)d_in[0];
    const float* weight   = (const float*)d_in[1];
    const float* bias     = (const float*)d_in[2];
    const float* ln_gamma = (const float*)d_in[3];
    const float* ln_beta  = (const float*)d_in[4];
    const int*   edge_src = (const int*)d_in[5];
    float* out = (float*)d_out;
    (void)d_ws; (void)ws_size;       // workspace unused: everything is in LDS

    mono<<<128, 512, 0, stream>>>(x, weight, edge_src, bias,
                                  ln_gamma, ln_beta, out);
}

// Round 8
// 133.735 us; speedup vs baseline: 1.4240x; 1.4240x over previous
//
#include <hip/hip_runtime.h>

// LAYER_IDX = [0, 4096, 6144, 7168, 7680, 7682]
// L1: 4096->2048 ebase 0       | L2: 2048->1024 ebase 262144
// L3: 1024->512  ebase 393216  | out: 512->2    ebase 458752 (total 459008)
// v8: single monolith (per-batch-column independence -> no grid sync), now
// 256 blocks x 1024 threads x 2 cols/block (fills all 256 CUs, 16 waves/CU)
// + pre-packed 4B edges {u16 src-base | f16 w} to halve edge L2 traffic.
#define FAN_IN 128
#define EPS 1e-5f
#define NEDGE 459008

typedef unsigned short u16;
typedef unsigned int u32;

__device__ __forceinline__ u16 f2bf(float f) {   // fp32->bf16 RNE
    union { float f; u32 u; } v; v.f = f;
    u32 r = v.u + 0x7fffu + ((v.u >> 16) & 1u);
    return (u16)(r >> 16);
}
__device__ __forceinline__ float bflo(u32 u) { return __uint_as_float(u << 16); }
__device__ __forceinline__ float bfhi(u32 u) { return __uint_as_float(u & 0xffff0000u); }
__device__ __forceinline__ float f16tof(u32 hi) {      // hi = f16 bits in [15:0]
    union { _Float16 h; u16 b; } c; c.b = (u16)hi; return (float)c.h;
}

// ---------------------------------------------------------------------------
// packk: edges -> u32 {(u16)(src - layerbase) | f16(weight) << 16}
__global__ __launch_bounds__(1024) void packk(
    const int* __restrict__ edge_src, const float* __restrict__ weight,
    u32* __restrict__ pe) {
    const int e0 = (blockIdx.x * 1024 + threadIdx.x) * 4;
    if (e0 >= NEDGE) return;
    const int4 s4 = *(const int4*)(edge_src + e0);
    const float4 w4 = *(const float4*)(weight + e0);
    // layer boundaries are multiples of 4, a quad never straddles them
    const int base = e0 < 262144 ? 0 : (e0 < 393216 ? 4096
                   : (e0 < 458752 ? 6144 : 7168));
    union { _Float16 h; u16 b; } c;
    u32 p[4];
    c.h = (_Float16)w4.x; p[0] = (u32)(s4.x - base) | ((u32)c.b << 16);
    c.h = (_Float16)w4.y; p[1] = (u32)(s4.y - base) | ((u32)c.b << 16);
    c.h = (_Float16)w4.z; p[2] = (u32)(s4.z - base) | ((u32)c.b << 16);
    c.h = (_Float16)w4.w; p[3] = (u32)(s4.w - base) | ((u32)c.b << 16);
    *(uint4*)(pe + e0) = *(const uint4*)p;
}

// block stats over 16 waves: in sA0,sA1,sQ0,sQ1 -> MR[4] = {m0,m1,r0,r1}
#define STATS_REDUCE(INVM)                                                    \
    {                                                                         \
        _Pragma("unroll")                                                     \
        for (int o = 32; o; o >>= 1) {                                        \
            sA0 += __shfl_down(sA0, o); sA1 += __shfl_down(sA1, o);           \
            sQ0 += __shfl_down(sQ0, o); sQ1 += __shfl_down(sQ1, o);           \
        }                                                                     \
        if (lane == 0) {                                                      \
            SW[wv][0] = sA0; SW[wv][1] = sA1;                                 \
            SW[wv][2] = sQ0; SW[wv][3] = sQ1;                                 \
        }                                                                     \
        __syncthreads();                                                      \
        if (tid < 2) {                                                        \
            float S = 0.f, Q = 0.f;                                           \
            _Pragma("unroll")                                                 \
            for (int w = 0; w < 16; ++w) { S += SW[w][tid]; Q += SW[w][2 + tid]; } \
            const float m = S * (INVM);                                       \
            MR[tid] = m;                                                      \
            MR[2 + tid] = rsqrtf(Q * (INVM) - m * m + EPS);                   \
        }                                                                     \
        __syncthreads();                                                      \
    }

// 4 packed edges against panel P -> acc (a0,a1) pair names given
#define EQUAD(E, P, A0n, A1n)                                                 \
    {                                                                         \
        const u32 v0 = P[(E).x & 0xffffu], v1 = P[(E).y & 0xffffu];           \
        const u32 v2 = P[(E).z & 0xffffu], v3 = P[(E).w & 0xffffu];           \
        const float w0 = f16tof((E).x >> 16), w1 = f16tof((E).y >> 16);       \
        const float w2 = f16tof((E).z >> 16), w3 = f16tof((E).w >> 16);       \
        A0n = fmaf(w0, bflo(v0), A0n); A1n = fmaf(w0, bfhi(v0), A1n);         \
        A0n = fmaf(w1, bflo(v1), A0n); A1n = fmaf(w1, bfhi(v1), A1n);         \
        A0n = fmaf(w2, bflo(v2), A0n); A1n = fmaf(w2, bfhi(v2), A1n);         \
        A0n = fmaf(w3, bflo(v3), A0n); A1n = fmaf(w3, bfhi(v3), A1n);         \
    }

// ---------------------------------------------------------------------------
__global__ __launch_bounds__(1024, 4) void mono(
    const float* __restrict__ x, const u32* __restrict__ pe,
    const float* __restrict__ bias, const float* __restrict__ lng,
    const float* __restrict__ lnb, float* __restrict__ out) {
    __shared__ u32 A0[4096];         // 16 KB  x^T panel, u32 = 2 bf16 cols
    __shared__ u32 A1[2048];         //  8 KB
    __shared__ u32 A2[1024];         //  4 KB
    __shared__ u32 A3[512];          //  2 KB
    __shared__ float SW[16][4];
    __shared__ float MR[4];          // m0,m1,r0,r1
    __shared__ float OW[4][2];

    const int tid = threadIdx.x;
    const int wv = tid >> 6, lane = tid & 63;
    const int c0 = blockIdx.x * 2;

    // ---- stage x: 4 feats/thread x 2 cols ---------------------------------
    {
        const float4 v0 = *(const float4*)(x + (size_t)c0 * 4096 + tid * 4);
        const float4 v1 = *(const float4*)(x + (size_t)(c0 + 1) * 4096 + tid * 4);
        u32 p[4];
        p[0] = (u32)f2bf(v0.x) | ((u32)f2bf(v1.x) << 16);
        p[1] = (u32)f2bf(v0.y) | ((u32)f2bf(v1.y) << 16);
        p[2] = (u32)f2bf(v0.z) | ((u32)f2bf(v1.z) << 16);
        p[3] = (u32)f2bf(v0.w) | ((u32)f2bf(v1.w) << 16);
        *(uint4*)&A0[tid * 4] = *(const uint4*)p;
    }
    __syncthreads();

    float sA0, sA1, sQ0, sQ1;
    float p0a, p0b, p1a, p1b;        // per-phase accumulators (live across STATS)

    // ================= P1: layer 1 — 2 nodes/thread, interleaved ===========
    {
        const u32* e0p = pe + (size_t)tid * FAN_IN;
        const u32* e1p = pe + (size_t)(tid + 1024) * FAN_IN;
        p0a = p0b = p1a = p1b = 0.f;
#pragma unroll 2
        for (int k = 0; k < FAN_IN; k += 4) {
            const uint4 eA = *(const uint4*)(e0p + k);
            const uint4 eB = *(const uint4*)(e1p + k);
            EQUAD(eA, A0, p0a, p0b);
            EQUAD(eB, A0, p1a, p1b);
        }
        const float bv0 = bias[tid], bv1 = bias[tid + 1024];
        p0a += bv0; p0b += bv0; p1a += bv1; p1b += bv1;
        sA0 = p0a + p1a; sA1 = p0b + p1b;
        sQ0 = p0a * p0a + p1a * p1a; sQ1 = p0b * p0b + p1b * p1b;
    }
    STATS_REDUCE(1.f / 2048.f);
    {
        const float m0 = MR[0], m1 = MR[1], r0 = MR[2], r1 = MR[3];
        const float g0 = lng[tid], b0 = lnb[tid];
        const float g1 = lng[tid + 1024], b1 = lnb[tid + 1024];
        A1[tid] = (u32)f2bf(fmaxf(fmaf(g0 * (p0a - m0), r0, b0), 0.f))
                | ((u32)f2bf(fmaxf(fmaf(g0 * (p0b - m1), r1, b0), 0.f)) << 16);
        A1[tid + 1024] = (u32)f2bf(fmaxf(fmaf(g1 * (p1a - m0), r0, b1), 0.f))
                | ((u32)f2bf(fmaxf(fmaf(g1 * (p1b - m1), r1, b1), 0.f)) << 16);
    }
    __syncthreads();

    // ================= P2: layer 2 — 1 node/thread =========================
    {
        const u32* ep = pe + 262144 + (size_t)tid * FAN_IN;
        p0a = p0b = 0.f;
#pragma unroll 4
        for (int k = 0; k < FAN_IN; k += 4) {
            const uint4 e = *(const uint4*)(ep + k);
            EQUAD(e, A1, p0a, p0b);
        }
        const float bv = bias[2048 + tid];
        p0a += bv; p0b += bv;
        sA0 = p0a; sA1 = p0b; sQ0 = p0a * p0a; sQ1 = p0b * p0b;
    }
    STATS_REDUCE(1.f / 1024.f);
    {
        const float m0 = MR[0], m1 = MR[1], r0 = MR[2], r1 = MR[3];
        const float g = lng[2048 + tid], b = lnb[2048 + tid];
        A2[tid] = (u32)f2bf(fmaxf(fmaf(g * (p0a - m0), r0, b), 0.f))
                | ((u32)f2bf(fmaxf(fmaf(g * (p0b - m1), r1, b), 0.f)) << 16);
    }
    __syncthreads();

    // ================= P3: layer 3 — thread-pair per node ==================
    {
        const int n = tid >> 1, half = tid & 1;
        const u32* ep = pe + 393216 + (size_t)n * FAN_IN + half * 64;
        p0a = p0b = 0.f;
#pragma unroll 4
        for (int k = 0; k < 64; k += 4) {
            const uint4 e = *(const uint4*)(ep + k);
            EQUAD(e, A2, p0a, p0b);
        }
        p0a += __shfl_xor(p0a, 1);   // combine the two halves (lanes 2j,2j+1)
        p0b += __shfl_xor(p0b, 1);
        const float bv = bias[3072 + n];
        p0a += bv; p0b += bv;
        if (half) { sA0 = sA1 = sQ0 = sQ1 = 0.f; }
        else      { sA0 = p0a; sA1 = p0b; sQ0 = p0a * p0a; sQ1 = p0b * p0b; }
    }
    STATS_REDUCE(1.f / 512.f);
    if (!(tid & 1)) {
        const int n = tid >> 1;
        const float m0 = MR[0], m1 = MR[1], r0 = MR[2], r1 = MR[3];
        const float g = lng[3072 + n], b = lnb[3072 + n];
        A3[n] = (u32)f2bf(fmaxf(fmaf(g * (p0a - m0), r0, b), 0.f))
              | ((u32)f2bf(fmaxf(fmaf(g * (p0b - m1), r1, b), 0.f)) << 16);
    }
    __syncthreads();

    // ================= P4: output — 2 targets x 128 edges x 2 cols =========
    if (tid < 256) {                 // waves 0,1 -> tgt0; waves 2,3 -> tgt1
        const int tgt = tid >> 7, k = tid & 127;
        const u32 e = pe[458752 + tgt * FAN_IN + k];
        const u32 v = A3[e & 0xffffu];
        const float w = f16tof(e >> 16);
        float o0 = w * bflo(v), o1 = w * bfhi(v);
#pragma unroll
        for (int o = 32; o; o >>= 1) {
            o0 += __shfl_down(o0, o); o1 += __shfl_down(o1, o);
        }
        if (lane == 0) { OW[wv][0] = o0; OW[wv][1] = o1; }
    }
    __syncthreads();
    if (tid < 4) {
        const int c = tid & 1, tg = tid >> 1;
        out[(size_t)(c0 + c) * 2 + tg] =
            OW[tg * 2][c] + OW[tg * 2 + 1][c] + bias[3584 + tg];
    }
}

// ---------------------------------------------------------------------------
extern "C" void kernel_launch(void* const* d_in, const int* in_sizes, int n_in,
                              void* d_out, int out_size, void* d_ws, size_t ws_size,
                              hipStream_t stream) {
    const float* x        = (const float*)d_in[0];
    const float* weight   = (const float*)d_in[1];
    const float* bias     = (const float*)d_in[2];
    const float* ln_gamma = (const float*)d_in[3];
    const float* ln_beta  = (const float*)d_in[4];
    const int*   edge_src = (const int*)d_in[5];
    float* out = (float*)d_out;

    u32* pe = (u32*)d_ws;            // packed edges, 459008 x 4B = 1.8 MB

    packk<<<113, 1024, 0, stream>>>(edge_src, weight, pe);
    mono<<<256, 1024, 0, stream>>>(x, pe, bias, ln_gamma, ln_beta, out);
}